// Round 6
// baseline (222.729 us; speedup 1.0000x reference)
//
#include <hip/hip_runtime.h>
#include <hip/hip_bf16.h>

#define BDIM 256
#define TB 64
#define OBS_D 17
#define HID 256
#define GHID 128
#define NM 16
#define NACT 6

typedef __attribute__((ext_vector_type(8))) short short8;
typedef __attribute__((ext_vector_type(4))) short short4v;
typedef __attribute__((ext_vector_type(4))) float f32x4;

// ws byte offsets (all 16B-aligned)
#define OFF_W1P    0u        // [4][256][8] bf16
#define OFF_W2P    16384u    // [32][256][8]
#define OFF_WG1P   147456u   // [32][128][8]
#define OFF_WG2P   212992u   // [16][16][8]
#define OFF_CP     217088u   // [32][16][8]  (whiten-folded centers)
#define OFF_MUWP   225280u   // [32][96][8]  col = a*16 + m
#define OFF_WV1P   274432u   // [32][256][8]
#define OFF_WV2P   405504u   // [32][256][8]
#define OFF_CNORM  536576u   // f32[16]
#define OFF_CCONST 536640u   // f32[16]
#define OFF_LSTDT  536704u   // f32[6][16]  lstdT[a][m] = log_std[m][a]

__device__ __forceinline__ float tanh_fast(float x){
  float e = __expf(2.f * x);
  return fmaf(-2.f, __builtin_amdgcn_rcpf(e + 1.f), 1.f);
}
__device__ __forceinline__ short bf16b(float x){
  __hip_bfloat16 h = __float2bfloat16(x);
  return *reinterpret_cast<short*>(&h);
}
__device__ __forceinline__ float b2f(short s){
  __hip_bfloat16 h = *reinterpret_cast<__hip_bfloat16*>(&s);
  return __bfloat162float(h);
}

__global__ void prep_kernel(const float* __restrict__ W1, const float* __restrict__ W2,
    const float* __restrict__ Wg1, const float* __restrict__ Wg2,
    const float* __restrict__ muW, const float* __restrict__ Wv1, const float* __restrict__ Wv2,
    const float* __restrict__ centers, const float* __restrict__ smean, const float* __restrict__ svar,
    const float* __restrict__ lstd, char* __restrict__ ws)
{
  __hip_bfloat16* w1p  = (__hip_bfloat16*)(ws + OFF_W1P);
  __hip_bfloat16* w2p  = (__hip_bfloat16*)(ws + OFF_W2P);
  __hip_bfloat16* wg1p = (__hip_bfloat16*)(ws + OFF_WG1P);
  __hip_bfloat16* wg2p = (__hip_bfloat16*)(ws + OFF_WG2P);
  __hip_bfloat16* cp   = (__hip_bfloat16*)(ws + OFF_CP);
  __hip_bfloat16* muwp = (__hip_bfloat16*)(ws + OFF_MUWP);
  __hip_bfloat16* wv1p = (__hip_bfloat16*)(ws + OFF_WV1P);
  __hip_bfloat16* wv2p = (__hip_bfloat16*)(ws + OFF_WV2P);
  float* cnorm  = (float*)(ws + OFF_CNORM);
  float* cconst = (float*)(ws + OFF_CCONST);
  float* lstdT  = (float*)(ws + OFF_LSTDT);

  int gid = blockIdx.x * blockDim.x + threadIdx.x;
  if (gid < NM){
    float s = 0.f; const float* c = centers + gid * HID;
    for (int k = 0; k < HID; ++k) s += c[k] * c[k];
    cnorm[gid] = s;
  } else if (gid < 2*NM){
    int m = gid - NM; float s = 0.f; const float* c = centers + m * HID;
    for (int k = 0; k < HID; ++k) s += smean[k] * rsqrtf(svar[k] + 1e-6f) * c[k];
    cconst[m] = s;
  } else if (gid < 2*NM + NACT*NM){
    int i = gid - 2*NM; int a = i / NM, m = i % NM;
    lstdT[a*NM + m] = lstd[m*NACT + a];
  }

  const int T0 = 8192, T1 = T0+65536, T2 = T1+32768, T3 = T2+2048,
            T4 = T3+4096, T5 = T4+24576, T6 = T5+65536, T7 = T6+65536;
  for (int i = gid; i < T7; i += gridDim.x * blockDim.x){
    float v; __hip_bfloat16* dst;
    if (i < T0){ int idx=i;    int kb8=idx/(256*8); int n=(idx/8)%256; int e=idx&7; int k=kb8*8+e;
      v = (k < OBS_D) ? W1[k*256+n] : 0.f; dst = &w1p[idx]; }
    else if (i < T1){ int idx=i-T0; int kb8=idx/(256*8); int n=(idx/8)%256; int e=idx&7; int k=kb8*8+e;
      v = W2[k*256+n]; dst = &w2p[idx]; }
    else if (i < T2){ int idx=i-T1; int kb8=idx/(128*8); int n=(idx/8)%128; int e=idx&7; int k=kb8*8+e;
      v = Wg1[k*128+n]; dst = &wg1p[idx]; }
    else if (i < T3){ int idx=i-T2; int kb8=idx/(16*8);  int n=(idx/8)%16;  int e=idx&7; int k=kb8*8+e;
      v = Wg2[k*16+n]; dst = &wg2p[idx]; }
    else if (i < T4){ int idx=i-T3; int kb8=idx/(16*8);  int m=(idx/8)%16;  int e=idx&7; int k=kb8*8+e;
      v = centers[m*HID+k] * rsqrtf(svar[k] + 1e-6f); dst = &cp[idx]; }
    else if (i < T5){ int idx=i-T4; int kb8=idx/(96*8);  int n=(idx/8)%96;  int e=idx&7; int k=kb8*8+e;
      int a = n >> 4, m = n & 15;
      v = muW[m*(HID*NACT) + k*NACT + a]; dst = &muwp[idx]; }
    else if (i < T6){ int idx=i-T5; int kb8=idx/(256*8); int n=(idx/8)%256; int e=idx&7; int k=kb8*8+e;
      v = Wv1[k*256+n]; dst = &wv1p[idx]; }
    else            { int idx=i-T6; int kb8=idx/(256*8); int n=(idx/8)%256; int e=idx&7; int k=kb8*8+e;
      v = Wv2[k*256+n]; dst = &wv2p[idx]; }
    *dst = __float2bfloat16(v);
  }
}

// Swapped-operand orientation: mfma(A=weight-frag, B=activation-frag)
//   C: lane&15 = batch row (within 16-tile), (lane>>4)*4+reg = output col.
// Epilogues write 4 consecutive cols as one b64; reductions are in-reg + 2 shfl.
__global__ __launch_bounds__(BDIM, 2) void moe_kernel(
  const float* __restrict__ obs,
  const float* __restrict__ b1, const float* __restrict__ b2,
  const float* __restrict__ bg1, const float* __restrict__ bg2,
  const float* __restrict__ mub,
  const float* __restrict__ bv1, const float* __restrict__ bv2,
  const float* __restrict__ Wv3, const float* __restrict__ bv3,
  const float* __restrict__ smean, const float* __restrict__ svar,
  const char* __restrict__ ws, float* __restrict__ out, int Btot)
{
  const short8* w1p  = (const short8*)(ws + OFF_W1P);
  const short8* w2p  = (const short8*)(ws + OFF_W2P);
  const short8* wg1p = (const short8*)(ws + OFF_WG1P);
  const short8* wg2p = (const short8*)(ws + OFF_WG2P);
  const short8* cp   = (const short8*)(ws + OFF_CP);
  const short8* muwp = (const short8*)(ws + OFF_MUWP);
  const short8* wv1p = (const short8*)(ws + OFF_WV1P);
  const short8* wv2p = (const short8*)(ws + OFF_WV2P);
  const float* cnorm  = (const float*)(ws + OFF_CNORM);
  const float* cconst = (const float*)(ws + OFF_CCONST);
  const float* lstdT  = (const float*)(ws + OFF_LSTDT);

  const int tid = threadIdx.x;
  const int w = tid >> 6, lane = tid & 63, l16 = lane & 15, lk = lane >> 4;
  const int rowg0 = blockIdx.x * TB;

  __shared__ __hip_bfloat16 feat_s[32*64*8];   // 32KB [k8][row64][8]
  __shared__ __hip_bfloat16 sc_s[32*64*8];     // 32KB h1 -> t -> v1
  __shared__ float part_s[4][64];              // zn partials, then v partials
  __shared__ __hip_bfloat16 g_s[64*16];        // g (bf16) [row][m]

  // ---- obs B-fragments: lane l16 = batch row, k = lk*8+e (pad 17->32)
  short8 aO[4];
  #pragma unroll
  for (int bt = 0; bt < 4; ++bt){
    const float* orow = obs + (size_t)(rowg0 + bt*16 + l16) * OBS_D;
    #pragma unroll
    for (int e = 0; e < 8; ++e){ int k = lk*8 + e; float v = (k < OBS_D) ? orow[k] : 0.f; aO[bt][e] = bf16b(v); }
  }

  // ================ G1: h1^T = W1^T x obs^T ; wave w -> cols [w*64, w*64+64)
  #pragma unroll
  for (int ctl = 0; ctl < 4; ++ctl){
    const int c0 = (w*4+ctl)*16 + lk*4;
    short8 Aw = w1p[lk*256 + (w*4+ctl)*16 + l16];
    f32x4 b1v = *(const f32x4*)&b1[c0];
    #pragma unroll
    for (int bt = 0; bt < 4; ++bt){
      f32x4 acc = {0.f,0.f,0.f,0.f};
      acc = __builtin_amdgcn_mfma_f32_16x16x32_bf16(Aw, aO[bt], acc, 0,0,0);
      short4v pv;
      #pragma unroll
      for (int r = 0; r < 4; ++r) pv[r] = bf16b(tanh_fast(acc[r] + b1v[r]));
      *(short4v*)&sc_s[((c0>>3)*64 + bt*16 + l16)*8 + (c0&7)] = pv;
    }
  }
  __syncthreads();

  // ================ G2: feat, N-split cols; zn partials
  {
    f32x4 b2v[4], mnv[4], ivv[4];
    #pragma unroll
    for (int ctl = 0; ctl < 4; ++ctl){
      const int c0 = (w*4+ctl)*16 + lk*4;
      b2v[ctl] = *(const f32x4*)&b2[c0];
      mnv[ctl] = *(const f32x4*)&smean[c0];
      f32x4 sv = *(const f32x4*)&svar[c0];
      #pragma unroll
      for (int r = 0; r < 4; ++r) ivv[ctl][r] = rsqrtf(sv[r] + 1e-6f);
    }
    f32x4 acc2[4][4];
    #pragma unroll
    for (int i = 0; i < 4; ++i)
      #pragma unroll
      for (int j = 0; j < 4; ++j) acc2[i][j] = (f32x4){0.f,0.f,0.f,0.f};
    #pragma unroll
    for (int ck = 0; ck < 8; ++ck){
      short8 Bb[4];
      #pragma unroll
      for (int bt = 0; bt < 4; ++bt) Bb[bt] = *(const short8*)&sc_s[((ck*4+lk)*64 + bt*16 + l16)*8];
      #pragma unroll
      for (int ctl = 0; ctl < 4; ++ctl){
        short8 Aw = w2p[(ck*4+lk)*256 + (w*4+ctl)*16 + l16];
        #pragma unroll
        for (int bt = 0; bt < 4; ++bt)
          acc2[ctl][bt] = __builtin_amdgcn_mfma_f32_16x16x32_bf16(Aw, Bb[bt], acc2[ctl][bt], 0,0,0);
      }
    }
    float znp[4] = {0.f,0.f,0.f,0.f};
    #pragma unroll
    for (int ctl = 0; ctl < 4; ++ctl){
      const int c0 = (w*4+ctl)*16 + lk*4;
      #pragma unroll
      for (int bt = 0; bt < 4; ++bt){
        short4v pv;
        #pragma unroll
        for (int r = 0; r < 4; ++r){
          float tf = tanh_fast(acc2[ctl][bt][r] + b2v[ctl][r]);
          pv[r] = bf16b(tf);
          float z = (tf - mnv[ctl][r]) * ivv[ctl][r];
          znp[bt] += z * z;
        }
        *(short4v*)&feat_s[((c0>>3)*64 + bt*16 + l16)*8 + (c0&7)] = pv;
      }
    }
    #pragma unroll
    for (int bt = 0; bt < 4; ++bt){
      znp[bt] += __shfl_xor(znp[bt], 16, 64);
      znp[bt] += __shfl_xor(znp[bt], 32, 64);
    }
    if (lk == 0){
      #pragma unroll
      for (int bt = 0; bt < 4; ++bt) part_s[w][bt*16 + l16] = znp[bt];
    }
  }
  __syncthreads();

  // ================ G3 (t, wave cols w*32..+31) + G5 (center-dot, bt=w) fused
  f32x4 accD = {0.f,0.f,0.f,0.f};
  {
    f32x4 acc3[2][4];
    #pragma unroll
    for (int i = 0; i < 2; ++i)
      #pragma unroll
      for (int j = 0; j < 4; ++j) acc3[i][j] = (f32x4){0.f,0.f,0.f,0.f};
    #pragma unroll
    for (int ck = 0; ck < 8; ++ck){
      short8 Bb[4];
      #pragma unroll
      for (int bt = 0; bt < 4; ++bt) Bb[bt] = *(const short8*)&feat_s[((ck*4+lk)*64 + bt*16 + l16)*8];
      accD = __builtin_amdgcn_mfma_f32_16x16x32_bf16(cp[(ck*4+lk)*16 + l16], Bb[w], accD, 0,0,0);
      #pragma unroll
      for (int ctl = 0; ctl < 2; ++ctl){
        short8 Aw = wg1p[(ck*4+lk)*128 + (w*2+ctl)*16 + l16];
        #pragma unroll
        for (int bt = 0; bt < 4; ++bt)
          acc3[ctl][bt] = __builtin_amdgcn_mfma_f32_16x16x32_bf16(Aw, Bb[bt], acc3[ctl][bt], 0,0,0);
      }
    }
    #pragma unroll
    for (int ctl = 0; ctl < 2; ++ctl){
      const int c0 = (w*2+ctl)*16 + lk*4;
      f32x4 bgv = *(const f32x4*)&bg1[c0];
      #pragma unroll
      for (int bt = 0; bt < 4; ++bt){
        short4v pv;
        #pragma unroll
        for (int r = 0; r < 4; ++r) pv[r] = bf16b(tanh_fast(acc3[ctl][bt][r] + bgv[r]));
        *(short4v*)&sc_s[((c0>>3)*64 + bt*16 + l16)*8 + (c0&7)] = pv;
      }
    }
  }
  __syncthreads();

  // ================ G4 (logits, bt=w) + softmax + s_bar
  {
    f32x4 accL = {0.f,0.f,0.f,0.f};
    #pragma unroll
    for (int ks = 0; ks < 4; ++ks){
      short8 Bt = *(const short8*)&sc_s[((ks*4+lk)*64 + w*16 + l16)*8];
      accL = __builtin_amdgcn_mfma_f32_16x16x32_bf16(wg2p[(ks*4+lk)*16 + l16], Bt, accL, 0,0,0);
    }
    const int b = w*16 + l16;               // block-local batch row
    const int mbase = lk*4;                  // this lane's 4 experts
    f32x4 cn4  = *(const f32x4*)&cnorm[mbase];
    f32x4 cc4  = *(const f32x4*)&cconst[mbase];
    f32x4 bg24 = *(const f32x4*)&bg2[mbase];
    float znr = part_s[0][b] + part_s[1][b] + part_s[2][b] + part_s[3][b];
    float d2r[4], lgr[4];
    #pragma unroll
    for (int r = 0; r < 4; ++r){
      float dot = accD[r] - cc4[r];
      float d2 = fmaxf(znr + cn4[r] - 2.f*dot, 0.f);
      d2r[r] = d2;
      lgr[r] = accL[r] + bg24[r] - d2 * (1.f/576.f);
    }
    // argmin d2 (first-min index semantics)
    float mv = d2r[0]; int mi = mbase;
    #pragma unroll
    for (int r = 1; r < 4; ++r){ if (d2r[r] < mv){ mv = d2r[r]; mi = mbase + r; } }
    #pragma unroll
    for (int d = 16; d <= 32; d <<= 1){
      float ov = __shfl_xor(mv, d, 64); int oi = __shfl_xor(mi, d, 64);
      if (ov < mv || (ov == mv && oi < mi)){ mv = ov; mi = oi; }
    }
    float lgm[4];
    #pragma unroll
    for (int r = 0; r < 4; ++r)
      lgm[r] = (d2r[r] <= 576.f || mi == mbase + r) ? lgr[r] : -1e9f;
    float mx = fmaxf(fmaxf(lgm[0], lgm[1]), fmaxf(lgm[2], lgm[3]));
    mx = fmaxf(mx, __shfl_xor(mx, 16, 64));
    mx = fmaxf(mx, __shfl_xor(mx, 32, 64));
    float ev[4], s = 0.f;
    #pragma unroll
    for (int r = 0; r < 4; ++r){ ev[r] = __expf(lgm[r] - mx); s += ev[r]; }
    s += __shfl_xor(s, 16, 64);
    s += __shfl_xor(s, 32, 64);
    float rs = __builtin_amdgcn_rcpf(s);
    float g4[4];
    short4v gp;
    #pragma unroll
    for (int r = 0; r < 4; ++r){ g4[r] = ev[r] * rs; gp[r] = bf16b(g4[r]); }
    *(short4v*)&g_s[b*16 + mbase] = gp;
    // s_bar = clip(g @ log_std)
    #pragma unroll
    for (int a = 0; a < 6; ++a){
      f32x4 lt = *(const f32x4*)&lstdT[a*16 + mbase];
      float sb = g4[0]*lt[0] + g4[1]*lt[1] + g4[2]*lt[2] + g4[3]*lt[3];
      sb += __shfl_xor(sb, 16, 64);
      sb += __shfl_xor(sb, 32, 64);
      if (lk == 0)
        out[(size_t)6*Btot + (size_t)(rowg0 + b)*6 + a] = fminf(fmaxf(sb, -20.f), 2.f);
    }
  }
  __syncthreads();

  // ================ G6 (mu, action-split) + G7 (v1 -> sc), shared feat B-frags
  {
    const int na = (w < 2) ? 2 : 1;
    const int a0 = (w < 2) ? (w*2) : (w + 2);
    f32x4 accM[2][4], acc7[4][4];
    #pragma unroll
    for (int j = 0; j < 4; ++j){
      accM[0][j] = (f32x4){0.f,0.f,0.f,0.f}; accM[1][j] = (f32x4){0.f,0.f,0.f,0.f};
      #pragma unroll
      for (int i = 0; i < 4; ++i) acc7[i][j] = (f32x4){0.f,0.f,0.f,0.f};
    }
    #pragma unroll
    for (int ck = 0; ck < 8; ++ck){
      short8 Bb[4];
      #pragma unroll
      for (int bt = 0; bt < 4; ++bt) Bb[bt] = *(const short8*)&feat_s[((ck*4+lk)*64 + bt*16 + l16)*8];
      #pragma unroll
      for (int al = 0; al < 2; ++al){
        if (al < na){
          short8 Am = muwp[(ck*4+lk)*96 + (a0+al)*16 + l16];
          #pragma unroll
          for (int bt = 0; bt < 4; ++bt)
            accM[al][bt] = __builtin_amdgcn_mfma_f32_16x16x32_bf16(Am, Bb[bt], accM[al][bt], 0,0,0);
        }
      }
      #pragma unroll
      for (int ctl = 0; ctl < 4; ++ctl){
        short8 Av = wv1p[(ck*4+lk)*256 + (w*4+ctl)*16 + l16];
        #pragma unroll
        for (int bt = 0; bt < 4; ++bt)
          acc7[ctl][bt] = __builtin_amdgcn_mfma_f32_16x16x32_bf16(Av, Bb[bt], acc7[ctl][bt], 0,0,0);
      }
    }
    // v1 epilogue -> sc
    #pragma unroll
    for (int ctl = 0; ctl < 4; ++ctl){
      const int c0 = (w*4+ctl)*16 + lk*4;
      f32x4 bvv = *(const f32x4*)&bv1[c0];
      #pragma unroll
      for (int bt = 0; bt < 4; ++bt){
        short4v pv;
        #pragma unroll
        for (int r = 0; r < 4; ++r) pv[r] = bf16b(tanh_fast(acc7[ctl][bt][r] + bvv[r]));
        *(short4v*)&sc_s[((c0>>3)*64 + bt*16 + l16)*8 + (c0&7)] = pv;
      }
    }
    // mu epilogue: p = sum_m g[m]*(mus[m]+mub[m])
    #pragma unroll
    for (int al = 0; al < 2; ++al){
      if (al < na){
        const int a = a0 + al;
        float mb4[4];
        #pragma unroll
        for (int r = 0; r < 4; ++r) mb4[r] = mub[(lk*4+r)*6 + a];
        #pragma unroll
        for (int bt = 0; bt < 4; ++bt){
          short4v gv = *(const short4v*)&g_s[(bt*16+l16)*16 + lk*4];
          float p = 0.f;
          #pragma unroll
          for (int r = 0; r < 4; ++r) p += (accM[al][bt][r] + mb4[r]) * b2f(gv[r]);
          p += __shfl_xor(p, 16, 64);
          p += __shfl_xor(p, 32, 64);
          if (lk == 0) out[(size_t)(rowg0 + bt*16 + l16)*6 + a] = p;
        }
      }
    }
  }
  __syncthreads();

  // ================ G8: v = sum_c tanh(v1@Wv2+bv2)[c] * Wv3[c]
  {
    f32x4 acc8[4][4];
    #pragma unroll
    for (int i = 0; i < 4; ++i)
      #pragma unroll
      for (int j = 0; j < 4; ++j) acc8[i][j] = (f32x4){0.f,0.f,0.f,0.f};
    #pragma unroll
    for (int ck = 0; ck < 8; ++ck){
      short8 Bb[4];
      #pragma unroll
      for (int bt = 0; bt < 4; ++bt) Bb[bt] = *(const short8*)&sc_s[((ck*4+lk)*64 + bt*16 + l16)*8];
      #pragma unroll
      for (int ctl = 0; ctl < 4; ++ctl){
        short8 Aw = wv2p[(ck*4+lk)*256 + (w*4+ctl)*16 + l16];
        #pragma unroll
        for (int bt = 0; bt < 4; ++bt)
          acc8[ctl][bt] = __builtin_amdgcn_mfma_f32_16x16x32_bf16(Aw, Bb[bt], acc8[ctl][bt], 0,0,0);
      }
    }
    float vpp[4] = {0.f,0.f,0.f,0.f};
    #pragma unroll
    for (int ctl = 0; ctl < 4; ++ctl){
      const int c0 = (w*4+ctl)*16 + lk*4;
      f32x4 bvv = *(const f32x4*)&bv2[c0];
      f32x4 w3v = *(const f32x4*)&Wv3[c0];
      #pragma unroll
      for (int bt = 0; bt < 4; ++bt)
        #pragma unroll
        for (int r = 0; r < 4; ++r)
          vpp[bt] += tanh_fast(acc8[ctl][bt][r] + bvv[r]) * w3v[r];
    }
    #pragma unroll
    for (int bt = 0; bt < 4; ++bt){
      vpp[bt] += __shfl_xor(vpp[bt], 16, 64);
      vpp[bt] += __shfl_xor(vpp[bt], 32, 64);
    }
    if (lk == 0){
      #pragma unroll
      for (int bt = 0; bt < 4; ++bt) part_s[w][bt*16 + l16] = vpp[bt];
    }
  }
  __syncthreads();
  if (tid < 64)
    out[(size_t)12*Btot + rowg0 + tid] =
      part_s[0][tid] + part_s[1][tid] + part_s[2][tid] + part_s[3][tid] + bv3[0];
}

extern "C" void kernel_launch(void* const* d_in, const int* in_sizes, int n_in,
                              void* d_out, int out_size, void* d_ws, size_t ws_size,
                              hipStream_t stream){
  const float* obs = (const float*)d_in[0];
  const float* W1  = (const float*)d_in[1];  const float* b1  = (const float*)d_in[2];
  const float* W2  = (const float*)d_in[3];  const float* b2  = (const float*)d_in[4];
  const float* Wg1 = (const float*)d_in[5];  const float* bg1 = (const float*)d_in[6];
  const float* Wg2 = (const float*)d_in[7];  const float* bg2 = (const float*)d_in[8];
  const float* muW = (const float*)d_in[9];  const float* mub = (const float*)d_in[10];
  const float* lstd= (const float*)d_in[11];
  const float* Wv1 = (const float*)d_in[12]; const float* bv1 = (const float*)d_in[13];
  const float* Wv2 = (const float*)d_in[14]; const float* bv2 = (const float*)d_in[15];
  const float* Wv3 = (const float*)d_in[16]; const float* bv3 = (const float*)d_in[17];
  const float* centers = (const float*)d_in[18];
  const float* smean   = (const float*)d_in[19];
  const float* svar    = (const float*)d_in[20];
  int Btot = in_sizes[0] / OBS_D;
  char* ws = (char*)d_ws;

  hipLaunchKernelGGL(prep_kernel, dim3(512), dim3(256), 0, stream,
      W1, W2, Wg1, Wg2, muW, Wv1, Wv2, centers, smean, svar, lstd, ws);
  hipLaunchKernelGGL(moe_kernel, dim3(Btot / TB), dim3(BDIM), 0, stream,
      obs, b1, b2, bg1, bg2, mub, bv1, bv2, Wv3, bv3, smean, svar,
      (const char*)ws, (float*)d_out, Btot);
}

// Round 7
// 209.246 us; speedup vs baseline: 1.0644x; 1.0644x over previous
//
#include <hip/hip_runtime.h>
#include <hip/hip_bf16.h>

#define BDIM 512
#define TB 64
#define OBS_D 17
#define HID 256
#define GHID 128
#define NM 16
#define NACT 6

typedef __attribute__((ext_vector_type(8))) short short8;
typedef __attribute__((ext_vector_type(4))) float f32x4;

// ws byte offsets (all 16B-aligned)
#define OFF_W1P    0u        // [4][256][8] bf16
#define OFF_W2P    16384u    // [32][256][8]
#define OFF_WG1P   147456u   // [32][128][8]
#define OFF_WG2P   212992u   // [16][16][8]
#define OFF_CP     217088u   // [32][16][8]  (whiten-folded centers)
#define OFF_MUWP   225280u   // [32][96][8]  col = a*16 + m
#define OFF_WV1P   274432u   // [32][256][8]
#define OFF_WV2P   405504u   // [32][256][8]
#define OFF_CNORM  536576u   // f32[16]
#define OFF_CCONST 536640u   // f32[16]

__device__ __forceinline__ float tanh_fast(float x){
  float e = __expf(2.f * x);
  return fmaf(-2.f, __builtin_amdgcn_rcpf(e + 1.f), 1.f);
}
__device__ __forceinline__ short bf16b(float x){
  __hip_bfloat16 h = __float2bfloat16(x);
  return *reinterpret_cast<short*>(&h);
}

__global__ void prep_kernel(const float* __restrict__ W1, const float* __restrict__ W2,
    const float* __restrict__ Wg1, const float* __restrict__ Wg2,
    const float* __restrict__ muW, const float* __restrict__ Wv1, const float* __restrict__ Wv2,
    const float* __restrict__ centers, const float* __restrict__ smean, const float* __restrict__ svar,
    char* __restrict__ ws)
{
  __hip_bfloat16* w1p  = (__hip_bfloat16*)(ws + OFF_W1P);
  __hip_bfloat16* w2p  = (__hip_bfloat16*)(ws + OFF_W2P);
  __hip_bfloat16* wg1p = (__hip_bfloat16*)(ws + OFF_WG1P);
  __hip_bfloat16* wg2p = (__hip_bfloat16*)(ws + OFF_WG2P);
  __hip_bfloat16* cp   = (__hip_bfloat16*)(ws + OFF_CP);
  __hip_bfloat16* muwp = (__hip_bfloat16*)(ws + OFF_MUWP);
  __hip_bfloat16* wv1p = (__hip_bfloat16*)(ws + OFF_WV1P);
  __hip_bfloat16* wv2p = (__hip_bfloat16*)(ws + OFF_WV2P);
  float* cnorm  = (float*)(ws + OFF_CNORM);
  float* cconst = (float*)(ws + OFF_CCONST);

  int gid = blockIdx.x * blockDim.x + threadIdx.x;
  if (gid < NM){
    float s = 0.f; const float* c = centers + gid * HID;
    for (int k = 0; k < HID; ++k) s += c[k] * c[k];
    cnorm[gid] = s;
  } else if (gid < 2*NM){
    int m = gid - NM; float s = 0.f; const float* c = centers + m * HID;
    for (int k = 0; k < HID; ++k) s += smean[k] * rsqrtf(svar[k] + 1e-6f) * c[k];
    cconst[m] = s;
  }

  const int T0 = 8192, T1 = T0+65536, T2 = T1+32768, T3 = T2+2048,
            T4 = T3+4096, T5 = T4+24576, T6 = T5+65536, T7 = T6+65536;
  for (int i = gid; i < T7; i += gridDim.x * blockDim.x){
    float v; __hip_bfloat16* dst;
    if (i < T0){ int idx=i;    int kb8=idx/(256*8); int n=(idx/8)%256; int e=idx&7; int k=kb8*8+e;
      v = (k < OBS_D) ? W1[k*256+n] : 0.f; dst = &w1p[idx]; }
    else if (i < T1){ int idx=i-T0; int kb8=idx/(256*8); int n=(idx/8)%256; int e=idx&7; int k=kb8*8+e;
      v = W2[k*256+n]; dst = &w2p[idx]; }
    else if (i < T2){ int idx=i-T1; int kb8=idx/(128*8); int n=(idx/8)%128; int e=idx&7; int k=kb8*8+e;
      v = Wg1[k*128+n]; dst = &wg1p[idx]; }
    else if (i < T3){ int idx=i-T2; int kb8=idx/(16*8);  int n=(idx/8)%16;  int e=idx&7; int k=kb8*8+e;
      v = Wg2[k*16+n]; dst = &wg2p[idx]; }
    else if (i < T4){ int idx=i-T3; int kb8=idx/(16*8);  int m=(idx/8)%16;  int e=idx&7; int k=kb8*8+e;
      v = centers[m*HID+k] * rsqrtf(svar[k] + 1e-6f); dst = &cp[idx]; }
    else if (i < T5){ int idx=i-T4; int kb8=idx/(96*8);  int n=(idx/8)%96;  int e=idx&7; int k=kb8*8+e;
      int a = n >> 4, m = n & 15;
      v = muW[m*(HID*NACT) + k*NACT + a]; dst = &muwp[idx]; }
    else if (i < T6){ int idx=i-T5; int kb8=idx/(256*8); int n=(idx/8)%256; int e=idx&7; int k=kb8*8+e;
      v = Wv1[k*256+n]; dst = &wv1p[idx]; }
    else            { int idx=i-T6; int kb8=idx/(256*8); int n=(idx/8)%256; int e=idx&7; int k=kb8*8+e;
      v = Wv2[k*256+n]; dst = &wv2p[idx]; }
    *dst = __float2bfloat16(v);
  }
}

// 8 waves cooperate on 64 rows (R3 structure, finer N-split): same LDS (2 blocks/CU)
// but 16 waves/CU = 4/SIMD. All accumulators intra-phase (no cross-barrier liveness).
__global__ __launch_bounds__(BDIM, 4) void moe_kernel(
  const float* __restrict__ obs,
  const float* __restrict__ b1, const float* __restrict__ b2,
  const float* __restrict__ bg1, const float* __restrict__ bg2,
  const float* __restrict__ mub, const float* __restrict__ lstd,
  const float* __restrict__ bv1, const float* __restrict__ bv2,
  const float* __restrict__ Wv3, const float* __restrict__ bv3,
  const float* __restrict__ smean, const float* __restrict__ svar,
  const char* __restrict__ ws, float* __restrict__ out, int Btot)
{
  const short8* w1p  = (const short8*)(ws + OFF_W1P);
  const short8* w2p  = (const short8*)(ws + OFF_W2P);
  const short8* wg1p = (const short8*)(ws + OFF_WG1P);
  const short8* wg2p = (const short8*)(ws + OFF_WG2P);
  const short8* cp   = (const short8*)(ws + OFF_CP);
  const short8* muwp = (const short8*)(ws + OFF_MUWP);
  const short8* wv1p = (const short8*)(ws + OFF_WV1P);
  const short8* wv2p = (const short8*)(ws + OFF_WV2P);
  const float* cnorm  = (const float*)(ws + OFF_CNORM);
  const float* cconst = (const float*)(ws + OFF_CCONST);

  const int tid = threadIdx.x;
  const int w = tid >> 6, lane = tid & 63, l16 = lane & 15, lk = lane >> 4;
  const int rowg0 = blockIdx.x * TB;

  __shared__ __hip_bfloat16 feat_s[32*64*8];   // 32KB [k8][row64][8]
  __shared__ __hip_bfloat16 sc_s[32*64*8];     // 32KB h1 -> t(0-15)/v1hi(16-31) -> v1
  __shared__ float part_s[8][64];              // zn partials, then v partials
  __shared__ float g_s[64*17];                 // softmax weights, padded

  // ---- obs A-fragments (K padded 17->32)
  short8 aO[4];
  #pragma unroll
  for (int rt = 0; rt < 4; ++rt){
    const float* orow = obs + (size_t)(rowg0 + rt*16 + l16) * OBS_D;
    #pragma unroll
    for (int e = 0; e < 8; ++e){ int k = lk*8 + e; float v = (k < OBS_D) ? orow[k] : 0.f; aO[rt][e] = bf16b(v); }
  }

  // ================ P0: G1 — h1 = tanh(obs@W1+b1); wave w -> cols [w*32, w*32+32)
  #pragma unroll
  for (int ctl = 0; ctl < 2; ++ctl){
    const int ct = w*2 + ctl;
    short8 B = w1p[lk*256 + ct*16 + l16];
    const int col = ct*16 + l16; const float bb = b1[col];
    #pragma unroll
    for (int rt = 0; rt < 4; ++rt){
      f32x4 acc = {0.f,0.f,0.f,0.f};
      acc = __builtin_amdgcn_mfma_f32_16x16x32_bf16(aO[rt], B, acc, 0,0,0);
      #pragma unroll
      for (int r = 0; r < 4; ++r){
        int row = rt*16 + lk*4 + r;
        sc_s[((col>>3)*64 + row)*8 + (col&7)] = __float2bfloat16(tanh_fast(acc[r] + bb));
      }
    }
  }
  __syncthreads();

  // ================ P1: G2 — feat = tanh(h1@W2+b2), wave w -> cols [w*32,+32); zn partials
  {
    f32x4 acc2[2][4];
    #pragma unroll
    for (int i = 0; i < 2; ++i)
      #pragma unroll
      for (int j = 0; j < 4; ++j) acc2[i][j] = (f32x4){0.f,0.f,0.f,0.f};
    #pragma unroll
    for (int ck = 0; ck < 8; ++ck){
      short8 A[4];
      #pragma unroll
      for (int rt = 0; rt < 4; ++rt) A[rt] = *(const short8*)&sc_s[((ck*4+lk)*64 + rt*16 + l16)*8];
      #pragma unroll
      for (int ctl = 0; ctl < 2; ++ctl){
        short8 B = w2p[(ck*4+lk)*256 + (w*2+ctl)*16 + l16];
        #pragma unroll
        for (int rt = 0; rt < 4; ++rt)
          acc2[ctl][rt] = __builtin_amdgcn_mfma_f32_16x16x32_bf16(A[rt], B, acc2[ctl][rt], 0,0,0);
      }
    }
    float znp[16];
    #pragma unroll
    for (int i = 0; i < 16; ++i) znp[i] = 0.f;
    #pragma unroll
    for (int ctl = 0; ctl < 2; ++ctl){
      const int col = (w*2+ctl)*16 + l16;
      const float bb = b2[col], mn = smean[col], iv = rsqrtf(svar[col] + 1e-6f);
      #pragma unroll
      for (int rt = 0; rt < 4; ++rt){
        #pragma unroll
        for (int r = 0; r < 4; ++r){
          int row = rt*16 + lk*4 + r;
          float tf = tanh_fast(acc2[ctl][rt][r] + bb);
          feat_s[((col>>3)*64 + row)*8 + (col&7)] = __float2bfloat16(tf);
          float z = (tf - mn) * iv;
          znp[rt*4+r] += z * z;
        }
      }
    }
    #pragma unroll
    for (int d = 1; d < 16; d <<= 1){
      #pragma unroll
      for (int i = 0; i < 16; ++i) znp[i] += __shfl_xor(znp[i], d, 64);
    }
    if (l16 == 0){
      #pragma unroll
      for (int i = 0; i < 16; ++i) part_s[w][(i>>2)*16 + lk*4 + (i&3)] = znp[i];
    }
  }
  __syncthreads();

  // ================ P2: G3 — t = tanh(feat@Wg1+bg1), wave w -> cols [w*16,+16)
  //                 + G5 — center-dot for row-tile w (waves 0-3)
  f32x4 accD = {0.f,0.f,0.f,0.f};
  {
    f32x4 acc3[4];
    #pragma unroll
    for (int j = 0; j < 4; ++j) acc3[j] = (f32x4){0.f,0.f,0.f,0.f};
    #pragma unroll
    for (int ck = 0; ck < 8; ++ck){
      short8 A[4];
      #pragma unroll
      for (int rt = 0; rt < 4; ++rt) A[rt] = *(const short8*)&feat_s[((ck*4+lk)*64 + rt*16 + l16)*8];
      if (w < 4)
        accD = __builtin_amdgcn_mfma_f32_16x16x32_bf16(A[w], cp[(ck*4+lk)*16 + l16], accD, 0,0,0);
      short8 B = wg1p[(ck*4+lk)*128 + w*16 + l16];
      #pragma unroll
      for (int rt = 0; rt < 4; ++rt)
        acc3[rt] = __builtin_amdgcn_mfma_f32_16x16x32_bf16(A[rt], B, acc3[rt], 0,0,0);
    }
    const int col = w*16 + l16;
    const float bb = bg1[col];
    #pragma unroll
    for (int rt = 0; rt < 4; ++rt)
      #pragma unroll
      for (int r = 0; r < 4; ++r){
        int row = rt*16 + lk*4 + r;
        sc_s[((col>>3)*64 + row)*8 + (col&7)] = __float2bfloat16(tanh_fast(acc3[rt][r] + bb));
      }
  }
  __syncthreads();

  // ================ P3: waves 0-3: G4 + softmax + s_bar (rows w*16..+16)
  //                      waves 4-7: G7-upper — v1 cols [128,256) -> sc chunks 16-31
  if (w < 4){
    const int rw = w*16;
    f32x4 accL = {0.f,0.f,0.f,0.f};
    #pragma unroll
    for (int ks = 0; ks < 4; ++ks){
      short8 aT = *(const short8*)&sc_s[((ks*4+lk)*64 + rw + l16)*8];
      accL = __builtin_amdgcn_mfma_f32_16x16x32_bf16(aT, wg2p[(ks*4+lk)*16 + l16], accL, 0,0,0);
    }
    const float cn = cnorm[l16], cc = cconst[l16], bg2v = bg2[l16];
    float gw[4];
    #pragma unroll
    for (int r = 0; r < 4; ++r){
      int rowl = rw + lk*4 + r;
      float znr = 0.f;
      #pragma unroll
      for (int i = 0; i < 8; ++i) znr += part_s[i][rowl];
      float dot = accD[r] - cc;
      float d2 = fmaxf(znr + cn - 2.f*dot, 0.f);
      float lg = accL[r] + bg2v - d2 * (1.f/576.f);
      float mv = d2; int mi = l16;
      #pragma unroll
      for (int d = 1; d < 16; d <<= 1){
        float ov = __shfl_xor(mv, d, 64); int oi = __shfl_xor(mi, d, 64);
        if (ov < mv || (ov == mv && oi < mi)){ mv = ov; mi = oi; }
      }
      bool act = (d2 <= 576.f) || (mi == l16);
      lg = act ? lg : -1e9f;
      float mx = lg;
      #pragma unroll
      for (int d = 1; d < 16; d <<= 1) mx = fmaxf(mx, __shfl_xor(mx, d, 64));
      float ev = __expf(lg - mx);
      float sm = ev;
      #pragma unroll
      for (int d = 1; d < 16; d <<= 1) sm += __shfl_xor(sm, d, 64);
      gw[r] = ev * __builtin_amdgcn_rcpf(sm);
      g_s[rowl*17 + l16] = gw[r];
    }
    #pragma unroll
    for (int r = 0; r < 4; ++r){
      float sb[6];
      #pragma unroll
      for (int a = 0; a < 6; ++a) sb[a] = gw[r] * lstd[l16*6 + a];
      #pragma unroll
      for (int d = 1; d < 16; d <<= 1){
        #pragma unroll
        for (int a = 0; a < 6; ++a) sb[a] += __shfl_xor(sb[a], d, 64);
      }
      if (l16 == 0){
        int row = rowg0 + rw + lk*4 + r;
        #pragma unroll
        for (int a = 0; a < 6; ++a)
          out[(size_t)6*Btot + (size_t)row*6 + a] = fminf(fmaxf(sb[a], -20.f), 2.f);
      }
    }
  } else {
    f32x4 acc7[2][4];
    #pragma unroll
    for (int i = 0; i < 2; ++i)
      #pragma unroll
      for (int j = 0; j < 4; ++j) acc7[i][j] = (f32x4){0.f,0.f,0.f,0.f};
    #pragma unroll
    for (int ck = 0; ck < 8; ++ck){
      short8 A[4];
      #pragma unroll
      for (int rt = 0; rt < 4; ++rt) A[rt] = *(const short8*)&feat_s[((ck*4+lk)*64 + rt*16 + l16)*8];
      #pragma unroll
      for (int ctl = 0; ctl < 2; ++ctl){
        short8 B = wv1p[(ck*4+lk)*256 + (8 + (w-4)*2 + ctl)*16 + l16];
        #pragma unroll
        for (int rt = 0; rt < 4; ++rt)
          acc7[ctl][rt] = __builtin_amdgcn_mfma_f32_16x16x32_bf16(A[rt], B, acc7[ctl][rt], 0,0,0);
      }
    }
    #pragma unroll
    for (int ctl = 0; ctl < 2; ++ctl){
      const int col = (8 + (w-4)*2 + ctl)*16 + l16;
      const float bb = bv1[col];
      #pragma unroll
      for (int rt = 0; rt < 4; ++rt)
        #pragma unroll
        for (int r = 0; r < 4; ++r){
          int row = rt*16 + lk*4 + r;
          sc_s[((col>>3)*64 + row)*8 + (col&7)] = __float2bfloat16(tanh_fast(acc7[ctl][rt][r] + bb));
        }
    }
  }
  __syncthreads();

  // ================ P4: waves 0-3: G7-lower — v1 cols [0,128) -> sc chunks 0-15
  //                      waves 4-7: G6 — mu heads (action-split)
  if (w < 4){
    f32x4 acc7[2][4];
    #pragma unroll
    for (int i = 0; i < 2; ++i)
      #pragma unroll
      for (int j = 0; j < 4; ++j) acc7[i][j] = (f32x4){0.f,0.f,0.f,0.f};
    #pragma unroll
    for (int ck = 0; ck < 8; ++ck){
      short8 A[4];
      #pragma unroll
      for (int rt = 0; rt < 4; ++rt) A[rt] = *(const short8*)&feat_s[((ck*4+lk)*64 + rt*16 + l16)*8];
      #pragma unroll
      for (int ctl = 0; ctl < 2; ++ctl){
        short8 B = wv1p[(ck*4+lk)*256 + (w*2 + ctl)*16 + l16];
        #pragma unroll
        for (int rt = 0; rt < 4; ++rt)
          acc7[ctl][rt] = __builtin_amdgcn_mfma_f32_16x16x32_bf16(A[rt], B, acc7[ctl][rt], 0,0,0);
      }
    }
    #pragma unroll
    for (int ctl = 0; ctl < 2; ++ctl){
      const int col = (w*2 + ctl)*16 + l16;
      const float bb = bv1[col];
      #pragma unroll
      for (int rt = 0; rt < 4; ++rt)
        #pragma unroll
        for (int r = 0; r < 4; ++r){
          int row = rt*16 + lk*4 + r;
          sc_s[((col>>3)*64 + row)*8 + (col&7)] = __float2bfloat16(tanh_fast(acc7[ctl][rt][r] + bb));
        }
    }
  } else {
    const int na = (w < 6) ? 2 : 1;
    const int a0 = (w < 6) ? (w-4)*2 : (w-2);   // w4:{0,1} w5:{2,3} w6:{4} w7:{5}
    f32x4 accM[2][4];
    #pragma unroll
    for (int i = 0; i < 2; ++i)
      #pragma unroll
      for (int j = 0; j < 4; ++j) accM[i][j] = (f32x4){0.f,0.f,0.f,0.f};
    #pragma unroll
    for (int ck = 0; ck < 8; ++ck){
      short8 A[4];
      #pragma unroll
      for (int rt = 0; rt < 4; ++rt) A[rt] = *(const short8*)&feat_s[((ck*4+lk)*64 + rt*16 + l16)*8];
      #pragma unroll
      for (int al = 0; al < 2; ++al){
        if (al < na){
          short8 B = muwp[(ck*4+lk)*96 + (a0+al)*16 + l16];
          #pragma unroll
          for (int rt = 0; rt < 4; ++rt)
            accM[al][rt] = __builtin_amdgcn_mfma_f32_16x16x32_bf16(A[rt], B, accM[al][rt], 0,0,0);
        }
      }
    }
    #pragma unroll
    for (int al = 0; al < 2; ++al){
      if (al < na){
        const int a = a0 + al;
        const float mubv = mub[l16*6 + a];
        #pragma unroll
        for (int rt = 0; rt < 4; ++rt){
          #pragma unroll
          for (int r = 0; r < 4; ++r){
            int row = rt*16 + lk*4 + r;
            float m = (accM[al][rt][r] + mubv) * g_s[row*17 + l16];
            #pragma unroll
            for (int d = 1; d < 16; d <<= 1) m += __shfl_xor(m, d, 64);
            if (l16 == 0) out[(size_t)(rowg0 + row)*6 + a] = m;
          }
        }
      }
    }
  }
  __syncthreads();

  // ================ P5: G8 — v partials; wave w -> cols [w*32,+32)
  {
    f32x4 acc8[2][4];
    #pragma unroll
    for (int i = 0; i < 2; ++i)
      #pragma unroll
      for (int j = 0; j < 4; ++j) acc8[i][j] = (f32x4){0.f,0.f,0.f,0.f};
    #pragma unroll
    for (int ck = 0; ck < 8; ++ck){
      short8 A[4];
      #pragma unroll
      for (int rt = 0; rt < 4; ++rt) A[rt] = *(const short8*)&sc_s[((ck*4+lk)*64 + rt*16 + l16)*8];
      #pragma unroll
      for (int ctl = 0; ctl < 2; ++ctl){
        short8 B = wv2p[(ck*4+lk)*256 + (w*2+ctl)*16 + l16];
        #pragma unroll
        for (int rt = 0; rt < 4; ++rt)
          acc8[ctl][rt] = __builtin_amdgcn_mfma_f32_16x16x32_bf16(A[rt], B, acc8[ctl][rt], 0,0,0);
      }
    }
    float vpp[16];
    #pragma unroll
    for (int i = 0; i < 16; ++i) vpp[i] = 0.f;
    #pragma unroll
    for (int ctl = 0; ctl < 2; ++ctl){
      const int col = (w*2+ctl)*16 + l16;
      const float bb = bv2[col], w3 = Wv3[col];
      #pragma unroll
      for (int rt = 0; rt < 4; ++rt)
        #pragma unroll
        for (int r = 0; r < 4; ++r)
          vpp[rt*4+r] += tanh_fast(acc8[ctl][rt][r] + bb) * w3;
    }
    #pragma unroll
    for (int d = 1; d < 16; d <<= 1){
      #pragma unroll
      for (int i = 0; i < 16; ++i) vpp[i] += __shfl_xor(vpp[i], d, 64);
    }
    if (l16 == 0){
      #pragma unroll
      for (int i = 0; i < 16; ++i) part_s[w][(i>>2)*16 + lk*4 + (i&3)] = vpp[i];
    }
  }
  __syncthreads();
  if (tid < 64){
    float v = bv3[0];
    #pragma unroll
    for (int i = 0; i < 8; ++i) v += part_s[i][tid];
    out[(size_t)12*Btot + rowg0 + tid] = v;
  }
}

extern "C" void kernel_launch(void* const* d_in, const int* in_sizes, int n_in,
                              void* d_out, int out_size, void* d_ws, size_t ws_size,
                              hipStream_t stream){
  const float* obs = (const float*)d_in[0];
  const float* W1  = (const float*)d_in[1];  const float* b1  = (const float*)d_in[2];
  const float* W2  = (const float*)d_in[3];  const float* b2  = (const float*)d_in[4];
  const float* Wg1 = (const float*)d_in[5];  const float* bg1 = (const float*)d_in[6];
  const float* Wg2 = (const float*)d_in[7];  const float* bg2 = (const float*)d_in[8];
  const float* muW = (const float*)d_in[9];  const float* mub = (const float*)d_in[10];
  const float* lstd= (const float*)d_in[11];
  const float* Wv1 = (const float*)d_in[12]; const float* bv1 = (const float*)d_in[13];
  const float* Wv2 = (const float*)d_in[14]; const float* bv2 = (const float*)d_in[15];
  const float* Wv3 = (const float*)d_in[16]; const float* bv3 = (const float*)d_in[17];
  const float* centers = (const float*)d_in[18];
  const float* smean   = (const float*)d_in[19];
  const float* svar    = (const float*)d_in[20];
  int Btot = in_sizes[0] / OBS_D;
  char* ws = (char*)d_ws;

  hipLaunchKernelGGL(prep_kernel, dim3(512), dim3(256), 0, stream,
      W1, W2, Wg1, Wg2, muW, Wv1, Wv2, centers, smean, svar, ws);
  hipLaunchKernelGGL(moe_kernel, dim3(Btot / TB), dim3(BDIM), 0, stream,
      obs, b1, b2, bg1, bg2, mub, lstd, bv1, bv2, Wv3, bv3, smean, svar,
      (const char*)ws, (float*)d_out, Btot);
}

// Round 8
// 185.395 us; speedup vs baseline: 1.2014x; 1.1286x over previous
//
#include <hip/hip_runtime.h>
#include <hip/hip_bf16.h>

#define BDIM 512
#define TB 64
#define OBS_D 17
#define HID 256
#define GHID 128
#define NM 16
#define NACT 6

typedef __attribute__((ext_vector_type(8))) short short8;
typedef __attribute__((ext_vector_type(4))) float f32x4;

// ws byte offsets (all 16B-aligned)
#define OFF_W1P    0u        // [4][256][8] bf16
#define OFF_W2P    16384u    // [32][256][8]
#define OFF_WG1P   147456u   // [32][128][8]
#define OFF_WG2P   212992u   // [16][16][8]
#define OFF_CP     217088u   // [32][16][8]  (whiten-folded centers)
#define OFF_MUWP   225280u   // [32][96][8]  col = a*16 + m
#define OFF_WV1P   274432u   // [32][256][8]
#define OFF_WV2P   405504u   // [32][256][8]
#define OFF_CNORM  536576u   // f32[16]
#define OFF_CCONST 536640u   // f32[16]

__device__ __forceinline__ float tanh_fast(float x){
  float e = __expf(2.f * x);
  return fmaf(-2.f, __builtin_amdgcn_rcpf(e + 1.f), 1.f);
}
__device__ __forceinline__ short bf16b(float x){
  __hip_bfloat16 h = __float2bfloat16(x);
  return *reinterpret_cast<short*>(&h);
}

__global__ void prep_kernel(const float* __restrict__ W1, const float* __restrict__ W2,
    const float* __restrict__ Wg1, const float* __restrict__ Wg2,
    const float* __restrict__ muW, const float* __restrict__ Wv1, const float* __restrict__ Wv2,
    const float* __restrict__ centers, const float* __restrict__ smean, const float* __restrict__ svar,
    char* __restrict__ ws)
{
  __hip_bfloat16* w1p  = (__hip_bfloat16*)(ws + OFF_W1P);
  __hip_bfloat16* w2p  = (__hip_bfloat16*)(ws + OFF_W2P);
  __hip_bfloat16* wg1p = (__hip_bfloat16*)(ws + OFF_WG1P);
  __hip_bfloat16* wg2p = (__hip_bfloat16*)(ws + OFF_WG2P);
  __hip_bfloat16* cp   = (__hip_bfloat16*)(ws + OFF_CP);
  __hip_bfloat16* muwp = (__hip_bfloat16*)(ws + OFF_MUWP);
  __hip_bfloat16* wv1p = (__hip_bfloat16*)(ws + OFF_WV1P);
  __hip_bfloat16* wv2p = (__hip_bfloat16*)(ws + OFF_WV2P);
  float* cnorm  = (float*)(ws + OFF_CNORM);
  float* cconst = (float*)(ws + OFF_CCONST);

  int gid = blockIdx.x * blockDim.x + threadIdx.x;
  if (gid < NM){
    float s = 0.f; const float* c = centers + gid * HID;
    for (int k = 0; k < HID; ++k) s += c[k] * c[k];
    cnorm[gid] = s;
  } else if (gid < 2*NM){
    int m = gid - NM; float s = 0.f; const float* c = centers + m * HID;
    for (int k = 0; k < HID; ++k) s += smean[k] * rsqrtf(svar[k] + 1e-6f) * c[k];
    cconst[m] = s;
  }

  const int T0 = 8192, T1 = T0+65536, T2 = T1+32768, T3 = T2+2048,
            T4 = T3+4096, T5 = T4+24576, T6 = T5+65536, T7 = T6+65536;
  for (int i = gid; i < T7; i += gridDim.x * blockDim.x){
    float v; __hip_bfloat16* dst;
    if (i < T0){ int idx=i;    int kb8=idx/(256*8); int n=(idx/8)%256; int e=idx&7; int k=kb8*8+e;
      v = (k < OBS_D) ? W1[k*256+n] : 0.f; dst = &w1p[idx]; }
    else if (i < T1){ int idx=i-T0; int kb8=idx/(256*8); int n=(idx/8)%256; int e=idx&7; int k=kb8*8+e;
      v = W2[k*256+n]; dst = &w2p[idx]; }
    else if (i < T2){ int idx=i-T1; int kb8=idx/(128*8); int n=(idx/8)%128; int e=idx&7; int k=kb8*8+e;
      v = Wg1[k*128+n]; dst = &wg1p[idx]; }
    else if (i < T3){ int idx=i-T2; int kb8=idx/(16*8);  int n=(idx/8)%16;  int e=idx&7; int k=kb8*8+e;
      v = Wg2[k*16+n]; dst = &wg2p[idx]; }
    else if (i < T4){ int idx=i-T3; int kb8=idx/(16*8);  int m=(idx/8)%16;  int e=idx&7; int k=kb8*8+e;
      v = centers[m*HID+k] * rsqrtf(svar[k] + 1e-6f); dst = &cp[idx]; }
    else if (i < T5){ int idx=i-T4; int kb8=idx/(96*8);  int n=(idx/8)%96;  int e=idx&7; int k=kb8*8+e;
      int a = n >> 4, m = n & 15;
      v = muW[m*(HID*NACT) + k*NACT + a]; dst = &muwp[idx]; }
    else if (i < T6){ int idx=i-T5; int kb8=idx/(256*8); int n=(idx/8)%256; int e=idx&7; int k=kb8*8+e;
      v = Wv1[k*256+n]; dst = &wv1p[idx]; }
    else            { int idx=i-T6; int kb8=idx/(256*8); int n=(idx/8)%256; int e=idx&7; int k=kb8*8+e;
      v = Wv2[k*256+n]; dst = &wv2p[idx]; }
    *dst = __float2bfloat16(v);
  }
}

// 8 waves on 64 rows, 2x4 (row x col) wave grid: wr = w>>2 owns 32 rows,
// wc = w&3 owns quarter-N. Per-wave fixed work (A-loads, shuffle chains,
// epilogues) halves vs R3; only B-loads duplicate 2x. 16 waves/CU.
__global__ __launch_bounds__(BDIM, 4) void moe_kernel(
  const float* __restrict__ obs,
  const float* __restrict__ b1, const float* __restrict__ b2,
  const float* __restrict__ bg1, const float* __restrict__ bg2,
  const float* __restrict__ mub, const float* __restrict__ lstd,
  const float* __restrict__ bv1, const float* __restrict__ bv2,
  const float* __restrict__ Wv3, const float* __restrict__ bv3,
  const float* __restrict__ smean, const float* __restrict__ svar,
  const char* __restrict__ ws, float* __restrict__ out, int Btot)
{
  const short8* w1p  = (const short8*)(ws + OFF_W1P);
  const short8* w2p  = (const short8*)(ws + OFF_W2P);
  const short8* wg1p = (const short8*)(ws + OFF_WG1P);
  const short8* wg2p = (const short8*)(ws + OFF_WG2P);
  const short8* cp   = (const short8*)(ws + OFF_CP);
  const short8* muwp = (const short8*)(ws + OFF_MUWP);
  const short8* wv1p = (const short8*)(ws + OFF_WV1P);
  const short8* wv2p = (const short8*)(ws + OFF_WV2P);
  const float* cnorm  = (const float*)(ws + OFF_CNORM);
  const float* cconst = (const float*)(ws + OFF_CCONST);

  const int tid = threadIdx.x;
  const int w = tid >> 6, lane = tid & 63, l16 = lane & 15, lk = lane >> 4;
  const int wr = w >> 2, wc = w & 3;
  const int rowg0 = blockIdx.x * TB;
  const int rbase = wr * 32;                   // wave's row base (2 row-tiles)

  __shared__ __hip_bfloat16 feat_s[32*64*8];   // 32KB [k8][row64][8]
  __shared__ __hip_bfloat16 sc_s[32*64*8];     // 32KB h1 -> t(ch0-15)/v1hi(ch16-31) -> v1
  __shared__ float part_s[8][64];              // zn partials, then v partials
  __shared__ float g_s[64*17];                 // softmax weights (f32, padded)

  // ---- obs A-fragments for this wave's 2 row-tiles (K padded 17->32)
  short8 aO[2];
  #pragma unroll
  for (int rt = 0; rt < 2; ++rt){
    const float* orow = obs + (size_t)(rowg0 + rbase + rt*16 + l16) * OBS_D;
    #pragma unroll
    for (int e = 0; e < 8; ++e){ int k = lk*8 + e; float v = (k < OBS_D) ? orow[k] : 0.f; aO[rt][e] = bf16b(v); }
  }

  // ================ P0: G1 — h1; wave (wr,wc): cols [wc*64,+64), rows [rbase,+32)
  #pragma unroll
  for (int ctl = 0; ctl < 4; ++ctl){
    const int ct = wc*4 + ctl;
    short8 B = w1p[lk*256 + ct*16 + l16];
    const int col = ct*16 + l16; const float bb = b1[col];
    #pragma unroll
    for (int rt = 0; rt < 2; ++rt){
      f32x4 acc = {0.f,0.f,0.f,0.f};
      acc = __builtin_amdgcn_mfma_f32_16x16x32_bf16(aO[rt], B, acc, 0,0,0);
      #pragma unroll
      for (int r = 0; r < 4; ++r){
        int row = rbase + rt*16 + lk*4 + r;
        sc_s[((col>>3)*64 + row)*8 + (col&7)] = __float2bfloat16(tanh_fast(acc[r] + bb));
      }
    }
  }
  __syncthreads();

  // ================ P1: G2 — feat; zn partials
  {
    f32x4 acc2[4][2];
    #pragma unroll
    for (int i = 0; i < 4; ++i)
      #pragma unroll
      for (int j = 0; j < 2; ++j) acc2[i][j] = (f32x4){0.f,0.f,0.f,0.f};
    #pragma unroll
    for (int ck = 0; ck < 8; ++ck){
      short8 A[2];
      #pragma unroll
      for (int rt = 0; rt < 2; ++rt) A[rt] = *(const short8*)&sc_s[((ck*4+lk)*64 + rbase + rt*16 + l16)*8];
      #pragma unroll
      for (int ctl = 0; ctl < 4; ++ctl){
        short8 B = w2p[(ck*4+lk)*256 + (wc*4+ctl)*16 + l16];
        #pragma unroll
        for (int rt = 0; rt < 2; ++rt)
          acc2[ctl][rt] = __builtin_amdgcn_mfma_f32_16x16x32_bf16(A[rt], B, acc2[ctl][rt], 0,0,0);
      }
    }
    float znp[8];
    #pragma unroll
    for (int i = 0; i < 8; ++i) znp[i] = 0.f;
    #pragma unroll
    for (int ctl = 0; ctl < 4; ++ctl){
      const int col = (wc*4+ctl)*16 + l16;
      const float bb = b2[col], mn = smean[col], iv = rsqrtf(svar[col] + 1e-6f);
      #pragma unroll
      for (int rt = 0; rt < 2; ++rt){
        #pragma unroll
        for (int r = 0; r < 4; ++r){
          int row = rbase + rt*16 + lk*4 + r;
          float tf = tanh_fast(acc2[ctl][rt][r] + bb);
          feat_s[((col>>3)*64 + row)*8 + (col&7)] = __float2bfloat16(tf);
          float z = (tf - mn) * iv;
          znp[rt*4+r] += z * z;
        }
      }
    }
    #pragma unroll
    for (int d = 1; d < 16; d <<= 1){
      #pragma unroll
      for (int i = 0; i < 8; ++i) znp[i] += __shfl_xor(znp[i], d, 64);
    }
    if (l16 == 0){
      #pragma unroll
      for (int i = 0; i < 8; ++i) part_s[w][rbase + (i>>2)*16 + lk*4 + (i&3)] = znp[i];
    }
  }
  __syncthreads();

  // ================ P2: G3 — t (8 tiles, 2 per wc) + G5 — accD (wc<2, rt=wc rows)
  f32x4 accD = {0.f,0.f,0.f,0.f};
  {
    f32x4 acc3[2][2];
    #pragma unroll
    for (int i = 0; i < 2; ++i)
      #pragma unroll
      for (int j = 0; j < 2; ++j) acc3[i][j] = (f32x4){0.f,0.f,0.f,0.f};
    #pragma unroll
    for (int ck = 0; ck < 8; ++ck){
      short8 A[2];
      #pragma unroll
      for (int rt = 0; rt < 2; ++rt) A[rt] = *(const short8*)&feat_s[((ck*4+lk)*64 + rbase + rt*16 + l16)*8];
      if (wc < 2)
        accD = __builtin_amdgcn_mfma_f32_16x16x32_bf16(A[wc], cp[(ck*4+lk)*16 + l16], accD, 0,0,0);
      #pragma unroll
      for (int ctl = 0; ctl < 2; ++ctl){
        short8 B = wg1p[(ck*4+lk)*128 + (wc*2+ctl)*16 + l16];
        #pragma unroll
        for (int rt = 0; rt < 2; ++rt)
          acc3[ctl][rt] = __builtin_amdgcn_mfma_f32_16x16x32_bf16(A[rt], B, acc3[ctl][rt], 0,0,0);
      }
    }
    #pragma unroll
    for (int ctl = 0; ctl < 2; ++ctl){
      const int col = (wc*2+ctl)*16 + l16;
      const float bb = bg1[col];
      #pragma unroll
      for (int rt = 0; rt < 2; ++rt)
        #pragma unroll
        for (int r = 0; r < 4; ++r){
          int row = rbase + rt*16 + lk*4 + r;
          sc_s[((col>>3)*64 + row)*8 + (col&7)] = __float2bfloat16(tanh_fast(acc3[ctl][rt][r] + bb));
        }
    }
  }
  __syncthreads();

  // ================ P3: wc<2 -> G4+softmax+s_bar (rows rbase+wc*16..+16, own accD)
  //                      wc>=2 -> v1-upper (cols [128,256), 4 ct, 2 rt)
  if (wc < 2){
    const int rw = rbase + wc*16;
    f32x4 accL = {0.f,0.f,0.f,0.f};
    #pragma unroll
    for (int ks = 0; ks < 4; ++ks){
      short8 aT = *(const short8*)&sc_s[((ks*4+lk)*64 + rw + l16)*8];
      accL = __builtin_amdgcn_mfma_f32_16x16x32_bf16(aT, wg2p[(ks*4+lk)*16 + l16], accL, 0,0,0);
    }
    const float cn = cnorm[l16], cc = cconst[l16], bg2v = bg2[l16];
    float gw[4];
    #pragma unroll
    for (int r = 0; r < 4; ++r){
      int rowl = rw + lk*4 + r;
      float znr = part_s[wr*4+0][rowl] + part_s[wr*4+1][rowl]
                + part_s[wr*4+2][rowl] + part_s[wr*4+3][rowl];
      float dot = accD[r] - cc;
      float d2 = fmaxf(znr + cn - 2.f*dot, 0.f);
      float lg = accL[r] + bg2v - d2 * (1.f/576.f);
      float mv = d2; int mi = l16;
      #pragma unroll
      for (int d = 1; d < 16; d <<= 1){
        float ov = __shfl_xor(mv, d, 64); int oi = __shfl_xor(mi, d, 64);
        if (ov < mv || (ov == mv && oi < mi)){ mv = ov; mi = oi; }
      }
      bool act = (d2 <= 576.f) || (mi == l16);
      lg = act ? lg : -1e9f;
      float mx = lg;
      #pragma unroll
      for (int d = 1; d < 16; d <<= 1) mx = fmaxf(mx, __shfl_xor(mx, d, 64));
      float ev = __expf(lg - mx);
      float sm = ev;
      #pragma unroll
      for (int d = 1; d < 16; d <<= 1) sm += __shfl_xor(sm, d, 64);
      gw[r] = ev * __builtin_amdgcn_rcpf(sm);
      g_s[rowl*17 + l16] = gw[r];
    }
    #pragma unroll
    for (int r = 0; r < 4; ++r){
      float sb[6];
      #pragma unroll
      for (int a = 0; a < 6; ++a) sb[a] = gw[r] * lstd[l16*6 + a];
      #pragma unroll
      for (int d = 1; d < 16; d <<= 1){
        #pragma unroll
        for (int a = 0; a < 6; ++a) sb[a] += __shfl_xor(sb[a], d, 64);
      }
      if (l16 == 0){
        int row = rowg0 + rw + lk*4 + r;
        #pragma unroll
        for (int a = 0; a < 6; ++a)
          out[(size_t)6*Btot + (size_t)row*6 + a] = fminf(fmaxf(sb[a], -20.f), 2.f);
      }
    }
  } else {
    f32x4 acc7[4][2];
    #pragma unroll
    for (int i = 0; i < 4; ++i)
      #pragma unroll
      for (int j = 0; j < 2; ++j) acc7[i][j] = (f32x4){0.f,0.f,0.f,0.f};
    #pragma unroll
    for (int ck = 0; ck < 8; ++ck){
      short8 A[2];
      #pragma unroll
      for (int rt = 0; rt < 2; ++rt) A[rt] = *(const short8*)&feat_s[((ck*4+lk)*64 + rbase + rt*16 + l16)*8];
      #pragma unroll
      for (int ctl = 0; ctl < 4; ++ctl){
        short8 B = wv1p[(ck*4+lk)*256 + (8 + (wc-2)*4 + ctl)*16 + l16];
        #pragma unroll
        for (int rt = 0; rt < 2; ++rt)
          acc7[ctl][rt] = __builtin_amdgcn_mfma_f32_16x16x32_bf16(A[rt], B, acc7[ctl][rt], 0,0,0);
      }
    }
    #pragma unroll
    for (int ctl = 0; ctl < 4; ++ctl){
      const int col = (8 + (wc-2)*4 + ctl)*16 + l16;
      const float bb = bv1[col];
      #pragma unroll
      for (int rt = 0; rt < 2; ++rt)
        #pragma unroll
        for (int r = 0; r < 4; ++r){
          int row = rbase + rt*16 + lk*4 + r;
          sc_s[((col>>3)*64 + row)*8 + (col&7)] = __float2bfloat16(tanh_fast(acc7[ctl][rt][r] + bb));
        }
    }
  }
  __syncthreads();

  // ================ P4: wc<2 -> v1-lower (cols [0,128), 4 ct, 2 rt)
  //                      wc>=2 -> mu heads (3 actions each, 2 rt)
  if (wc < 2){
    f32x4 acc7[4][2];
    #pragma unroll
    for (int i = 0; i < 4; ++i)
      #pragma unroll
      for (int j = 0; j < 2; ++j) acc7[i][j] = (f32x4){0.f,0.f,0.f,0.f};
    #pragma unroll
    for (int ck = 0; ck < 8; ++ck){
      short8 A[2];
      #pragma unroll
      for (int rt = 0; rt < 2; ++rt) A[rt] = *(const short8*)&feat_s[((ck*4+lk)*64 + rbase + rt*16 + l16)*8];
      #pragma unroll
      for (int ctl = 0; ctl < 4; ++ctl){
        short8 B = wv1p[(ck*4+lk)*256 + (wc*4 + ctl)*16 + l16];
        #pragma unroll
        for (int rt = 0; rt < 2; ++rt)
          acc7[ctl][rt] = __builtin_amdgcn_mfma_f32_16x16x32_bf16(A[rt], B, acc7[ctl][rt], 0,0,0);
      }
    }
    #pragma unroll
    for (int ctl = 0; ctl < 4; ++ctl){
      const int col = (wc*4 + ctl)*16 + l16;
      const float bb = bv1[col];
      #pragma unroll
      for (int rt = 0; rt < 2; ++rt)
        #pragma unroll
        for (int r = 0; r < 4; ++r){
          int row = rbase + rt*16 + lk*4 + r;
          sc_s[((col>>3)*64 + row)*8 + (col&7)] = __float2bfloat16(tanh_fast(acc7[ctl][rt][r] + bb));
        }
    }
  } else {
    f32x4 accM[3][2];
    #pragma unroll
    for (int i = 0; i < 3; ++i)
      #pragma unroll
      for (int j = 0; j < 2; ++j) accM[i][j] = (f32x4){0.f,0.f,0.f,0.f};
    #pragma unroll
    for (int ck = 0; ck < 8; ++ck){
      short8 A[2];
      #pragma unroll
      for (int rt = 0; rt < 2; ++rt) A[rt] = *(const short8*)&feat_s[((ck*4+lk)*64 + rbase + rt*16 + l16)*8];
      #pragma unroll
      for (int al = 0; al < 3; ++al){
        short8 B = muwp[(ck*4+lk)*96 + ((wc-2)*3 + al)*16 + l16];
        #pragma unroll
        for (int rt = 0; rt < 2; ++rt)
          accM[al][rt] = __builtin_amdgcn_mfma_f32_16x16x32_bf16(A[rt], B, accM[al][rt], 0,0,0);
      }
    }
    #pragma unroll
    for (int al = 0; al < 3; ++al){
      const int a = (wc-2)*3 + al;
      const float mubv = mub[l16*6 + a];
      #pragma unroll
      for (int rt = 0; rt < 2; ++rt){
        #pragma unroll
        for (int r = 0; r < 4; ++r){
          int row = rbase + rt*16 + lk*4 + r;
          float m = (accM[al][rt][r] + mubv) * g_s[row*17 + l16];
          #pragma unroll
          for (int d = 1; d < 16; d <<= 1) m += __shfl_xor(m, d, 64);
          if (l16 == 0) out[(size_t)(rowg0 + row)*6 + a] = m;
        }
      }
    }
  }
  __syncthreads();

  // ================ P5: G8 — v partials; cols [wc*64,+64), rows [rbase,+32)
  {
    f32x4 acc8[4][2];
    #pragma unroll
    for (int i = 0; i < 4; ++i)
      #pragma unroll
      for (int j = 0; j < 2; ++j) acc8[i][j] = (f32x4){0.f,0.f,0.f,0.f};
    #pragma unroll
    for (int ck = 0; ck < 8; ++ck){
      short8 A[2];
      #pragma unroll
      for (int rt = 0; rt < 2; ++rt) A[rt] = *(const short8*)&sc_s[((ck*4+lk)*64 + rbase + rt*16 + l16)*8];
      #pragma unroll
      for (int ctl = 0; ctl < 4; ++ctl){
        short8 B = wv2p[(ck*4+lk)*256 + (wc*4+ctl)*16 + l16];
        #pragma unroll
        for (int rt = 0; rt < 2; ++rt)
          acc8[ctl][rt] = __builtin_amdgcn_mfma_f32_16x16x32_bf16(A[rt], B, acc8[ctl][rt], 0,0,0);
      }
    }
    float vpp[8];
    #pragma unroll
    for (int i = 0; i < 8; ++i) vpp[i] = 0.f;
    #pragma unroll
    for (int ctl = 0; ctl < 4; ++ctl){
      const int col = (wc*4+ctl)*16 + l16;
      const float bb = bv2[col], w3 = Wv3[col];
      #pragma unroll
      for (int rt = 0; rt < 2; ++rt)
        #pragma unroll
        for (int r = 0; r < 4; ++r)
          vpp[rt*4+r] += tanh_fast(acc8[ctl][rt][r] + bb) * w3;
    }
    #pragma unroll
    for (int d = 1; d < 16; d <<= 1){
      #pragma unroll
      for (int i = 0; i < 8; ++i) vpp[i] += __shfl_xor(vpp[i], d, 64);
    }
    if (l16 == 0){
      #pragma unroll
      for (int i = 0; i < 8; ++i) part_s[w][rbase + (i>>2)*16 + lk*4 + (i&3)] = vpp[i];
    }
  }
  __syncthreads();
  if (tid < 64){
    int g = tid >> 5;    // wr group of this row
    float v = part_s[g*4+0][tid] + part_s[g*4+1][tid]
            + part_s[g*4+2][tid] + part_s[g*4+3][tid] + bv3[0];
    out[(size_t)12*Btot + rowg0 + tid] = v;
  }
}

extern "C" void kernel_launch(void* const* d_in, const int* in_sizes, int n_in,
                              void* d_out, int out_size, void* d_ws, size_t ws_size,
                              hipStream_t stream){
  const float* obs = (const float*)d_in[0];
  const float* W1  = (const float*)d_in[1];  const float* b1  = (const float*)d_in[2];
  const float* W2  = (const float*)d_in[3];  const float* b2  = (const float*)d_in[4];
  const float* Wg1 = (const float*)d_in[5];  const float* bg1 = (const float*)d_in[6];
  const float* Wg2 = (const float*)d_in[7];  const float* bg2 = (const float*)d_in[8];
  const float* muW = (const float*)d_in[9];  const float* mub = (const float*)d_in[10];
  const float* lstd= (const float*)d_in[11];
  const float* Wv1 = (const float*)d_in[12]; const float* bv1 = (const float*)d_in[13];
  const float* Wv2 = (const float*)d_in[14]; const float* bv2 = (const float*)d_in[15];
  const float* Wv3 = (const float*)d_in[16]; const float* bv3 = (const float*)d_in[17];
  const float* centers = (const float*)d_in[18];
  const float* smean   = (const float*)d_in[19];
  const float* svar    = (const float*)d_in[20];
  int Btot = in_sizes[0] / OBS_D;
  char* ws = (char*)d_ws;

  hipLaunchKernelGGL(prep_kernel, dim3(512), dim3(256), 0, stream,
      W1, W2, Wg1, Wg2, muW, Wv1, Wv2, centers, smean, svar, ws);
  hipLaunchKernelGGL(moe_kernel, dim3(Btot / TB), dim3(BDIM), 0, stream,
      obs, b1, b2, bg1, bg2, mub, lstd, bv1, bv2, Wv3, bv3, smean, svar,
      (const char*)ws, (float*)d_out, Btot);
}